// Round 2
// baseline (333.374 us; speedup 1.0000x reference)
//
#include <hip/hip_runtime.h>
#include <math.h>

// Problem constants (from reference setup_inputs)
constexpr int B   = 2;
constexpr int P   = 19248;
constexpr int N   = 100;   // TOP_K_CONF
constexpr int K   = 20;    // TOP_K_IOU
constexpr int HP  = 138;   // proto H/W
constexpr int HPP = HP * HP;
constexpr int H   = 550;
constexpr int W   = 550;
constexpr int DM  = 32;    // mask dim
constexpr float EPS = 1e-6f;
constexpr int NBIN = 2048;      // histogram bins over f32 bitpattern >> 19
constexpr int CAND = 2048;      // candidate cap (expected ~150/batch)
constexpr int NPAIR = N * (N - 1) / 2;  // 4950

constexpr int GRID = 256;       // one block per CU -> all blocks co-resident
constexpr int TPB  = 512;       // 8 waves/block
constexpr int GT   = GRID * TPB;

// ---- persistent workspace layout: IDENTICAL footprint to the proven round-0
// kernel (60768 words = 243072 bytes). No word beyond OFS_FC+B*HPP is touched.
constexpr int IOFS_IDX  = 0;                        // int   [B,N] orig indices
constexpr int OFS_SCONF = IOFS_IDX + B * N;         // float [B,N]
constexpr int OFS_SLOC  = OFS_SCONF + B * N;        // float [B,N,4]
constexpr int OFS_IOU   = OFS_SLOC + B * N * 4;     // float [B,N,N] (upper tri)
constexpr int OFS_KLOC  = OFS_IOU + B * N * N;      // float [B,K,4]
constexpr int OFS_KMASK = OFS_KLOC + B * K * 4;     // float [B,K,DM]
constexpr int OFS_KCONF = OFS_KMASK + B * K * DM;   // float [B,K]
constexpr int OFS_FC    = OFS_KCONF + B * K;        // float [B,HP,HP]
// end = 60768 words

// Grid-barrier counter lives on IOU[0][0][0] — a diagonal element: Phase D
// writes only i<j, Phase E loads it but always discards (col>row mask).
constexpr int OFS_BAR = OFS_IOU;

// Scratch overlaid on the FC region (dead until Phase F overwrites it):
constexpr int SC_HIST  = OFS_FC;                    // int   [B,NBIN]
constexpr int SC_CNT   = SC_HIST + B * NBIN;        // int   [B]
constexpr int SC_CANDI = SC_CNT + B;                // int   [B,CAND]
constexpr int SC_CANDV = SC_CANDI + B * CAND;       // float [B,CAND]
// scratch end = OFS_FC + 12290 < OFS_FC + 38088  ✓

// ---- LDS union across phases (max ~41 KB < 64 KB static limit)
struct SmemB { int h[NBIN]; int c[NBIN / 16]; int T[B]; };
struct SmemC { float cv[CAND]; int ci[CAND]; float outv[N]; int outi[N]; };
struct SmemE { float siou[N * N]; float sconf[N]; unsigned int mbits[N];
               int keep[K]; float coef[K]; float red[TPB / 64]; };
struct SmemF { float kl[B * K * 4]; float kc[B * K]; float km[B * K * DM]; };
union  SmemU { SmemB b; SmemC c; SmemE e; SmemF f; float red[TPB / 64]; };

// Manual grid barrier: same single-thread ticket protocol as ROCm's
// __ockl_grid_sync (safe: all 256 blocks co-resident, 1 per CU).
__device__ __forceinline__ void gridbar(unsigned int* bar) {
  __syncthreads();                 // compiler drains vmcnt/lgkmcnt here
  if (threadIdx.x == 0) {
    __threadfence();               // release: publish this block's stores
    unsigned int tk = __hip_atomic_fetch_add(bar, 1u, __ATOMIC_RELEASE,
                                             __HIP_MEMORY_SCOPE_AGENT);
    unsigned int target = (tk / (unsigned)GRID + 1u) * (unsigned)GRID;
    while (__hip_atomic_load(bar, __ATOMIC_ACQUIRE,
                             __HIP_MEMORY_SCOPE_AGENT) < target)
      __builtin_amdgcn_s_sleep(2);
    __threadfence();               // acquire: invalidate caches
  }
  __syncthreads();
}

__global__ __launch_bounds__(TPB, 2) void k_fused(
    const float* __restrict__ original, const float* __restrict__ loc,
    const float* __restrict__ conf, const float* __restrict__ mask,
    const float* __restrict__ proto, float* wsf, int* wsi, float* out) {
  const int t   = threadIdx.x;
  const int bid = blockIdx.x;
  const int g   = bid * TPB + t;
  unsigned int* bar = (unsigned int*)&wsi[OFS_BAR];
  __shared__ SmemU sm;

  // ---------------- Phase A: sigmoid (softmax[...,1]) -> global histogram.
  // (hist+cnt zeroed by host-side hipMemsetAsync; bar counter too)
  if (g == 0) { out[0] = 0.0f; out[1] = 0.0f; }
  {
    const float2* c2 = (const float2*)conf;
    for (int q = g; q < B * P; q += GT) {
      float2 c = c2[q];
      float m  = fmaxf(c.x, c.y);
      float e0 = expf(c.x - m), e1 = expf(c.y - m);
      float v  = e1 / (e0 + e1);
      int b = (q >= P) ? 1 : 0;
      atomicAdd(&wsi[SC_HIST + b * NBIN + (int)(__float_as_uint(v) >> 19)], 1);
    }
  }
  gridbar(bar);  // 1

  // ---------------- Phase B: threshold (redundant per block) + compaction.
  for (int b = 0; b < B; b++) {
    for (int q = t; q < NBIN; q += TPB) sm.b.h[q] = wsi[SC_HIST + b * NBIN + q];
    __syncthreads();
    if (t < NBIN / 16) {
      int s = 0;
      for (int u = 0; u < 16; u++) s += sm.b.h[t * 16 + u];
      sm.b.c[t] = s;
    }
    __syncthreads();
    if (t == 0) {
      // smallest bin with cumulative-from-top >= N (== serial scan result)
      int acc = 0, ch = NBIN / 16 - 1;
      for (; ch >= 0; ch--) { int cs = sm.b.c[ch]; if (acc + cs >= N) break; acc += cs; }
      int T = -1;
      if (ch >= 0) {
        int bin = ch * 16 + 15;
        for (; bin >= ch * 16; bin--) { acc += sm.b.h[bin]; if (acc >= N) break; }
        T = bin;
      }
      sm.b.T[b] = T;
    }
    __syncthreads();
  }
  {
    const int T0 = sm.b.T[0], T1 = sm.b.T[1];
    const float2* c2 = (const float2*)conf;
    for (int q = g; q < B * P; q += GT) {
      float2 c = c2[q];
      float m  = fmaxf(c.x, c.y);
      float e0 = expf(c.x - m), e1 = expf(c.y - m);
      float v  = e1 / (e0 + e1);          // bit-identical recompute
      int b = (q >= P) ? 1 : 0;
      if ((int)(__float_as_uint(v) >> 19) >= (b ? T1 : T0)) {
        int pos = atomicAdd(&wsi[SC_CNT + b], 1);
        if (pos < CAND) {
          wsf[SC_CANDV + b * CAND + pos] = v;
          wsi[SC_CANDI + b * CAND + pos] = q - b * P;
        }
      }
    }
  }
  gridbar(bar);  // 2

  // ---------------- Phase C: rank-based stable top-N (blocks 0..B-1; M ~150)
  if (bid < B) {
    const int b = bid;
    const int M = min(wsi[SC_CNT + b], CAND);
    for (int q = t; q < M; q += TPB) {
      sm.c.cv[q] = wsf[SC_CANDV + b * CAND + q];
      sm.c.ci[q] = wsi[SC_CANDI + b * CAND + q];
    }
    __syncthreads();
    for (int c = t; c < M; c += TPB) {
      float mv = sm.c.cv[c]; int mi = sm.c.ci[c];
      int rank = 0;
      for (int j2 = 0; j2 < M; j2++) {
        float jv = sm.c.cv[j2]; int ji = sm.c.ci[j2];
        rank += (jv > mv || (jv == mv && ji < mi)) ? 1 : 0;  // val desc, idx asc
      }
      if (rank < N) { sm.c.outv[rank] = mv; sm.c.outi[rank] = mi; }
    }
    __syncthreads();
    if (t < N) {
      wsi[IOFS_IDX + b * N + t]  = sm.c.outi[t];
      wsf[OFS_SCONF + b * N + t] = sm.c.outv[t];
    }
    if (t < N * 4) {
      int k = t >> 2, d = t & 3;
      wsf[OFS_SLOC + (b * N + k) * 4 + d] = loc[(b * P + sm.c.outi[k]) * 4 + d];
    }
  }
  gridbar(bar);  // 3

  // ---------------- Phase D: gaussian IoU, one upper-tri pair per wave.
  // Reduction tree bit-identical to round-0's 256-thread kernel.
  {
    const int wid  = (bid << 3) + (t >> 6);   // 2048 waves
    const int lane = t & 63;
    for (int pr = wid; pr < B * NPAIR; pr += GRID * 8) {
      const int b = (pr >= NPAIR) ? 1 : 0;
      const int r = pr - b * NPAIR;
      int i = (int)((199.0f - sqrtf((float)(39601 - 8 * r))) * 0.5f);
      i = min(max(i, 0), N - 2);
      while (i < N - 2 && ((i + 1) * (2 * N - 2 - i)) / 2 <= r) i++;
      while (i > 0 && (i * (2 * N - 1 - i)) / 2 > r) i--;
      const int j = i + 1 + (r - (i * (2 * N - 1 - i)) / 2);

      const float4 li = *(const float4*)&wsf[OFS_SLOC + (b * N + i) * 4];
      const float4 lj = *(const float4*)&wsf[OFS_SLOC + (b * N + j) * 4];

      float smn[4], ssi[4], ssj[4];
#pragma unroll
      for (int w4 = 0; w4 < 4; w4++) {
        smn[w4] = 0.0f; ssi[w4] = 0.0f; ssj[w4] = 0.0f;
#pragma unroll
        for (int q = 0; q < 4; q++) {
          int pix = lane + (w4 << 6) + (q << 8);  // old thread (lane+64*w4), q-th px
          int y = pix >> 5, x = pix & 31;
          float xs = (x + 0.5f) / 32.0f, ys = (y + 0.5f) / 32.0f;
          float dxi = (xs - li.x) / (li.z + 1e-4f);
          float dyi = (ys - li.y) / (li.w + 1e-4f);
          float gi = expf(-0.5f * (dxi * dxi + dyi * dyi));
          float dxj = (xs - lj.x) / (lj.z + 1e-4f);
          float dyj = (ys - lj.y) / (lj.w + 1e-4f);
          float gj = expf(-0.5f * (dxj * dxj + dyj * dyj));
          smn[w4] += fminf(gi, gj);
          ssi[w4] += gi;
          ssj[w4] += gj;
        }
      }
#pragma unroll
      for (int off = 32; off > 0; off >>= 1) {
#pragma unroll
        for (int w4 = 0; w4 < 4; w4++) {
          smn[w4] += __shfl_down(smn[w4], off);
          ssi[w4] += __shfl_down(ssi[w4], off);
          ssj[w4] += __shfl_down(ssj[w4], off);
        }
      }
      if (lane == 0) {
        float inter = smn[0] + smn[1] + smn[2] + smn[3];
        float si    = ssi[0] + ssi[1] + ssi[2] + ssi[3];
        float sj    = ssj[0] + ssj[1] + ssj[2] + ssj[3];
        wsf[OFS_IOU + (b * N + i) * N + j] = inter / (si + sj - inter);
      }
    }
  }
  gridbar(bar);  // 4

  // ---------------- Phase E: NMS select + gathers + ae loss (blocks 0..B-1)
  if (bid < B) {
    const int b = bid;
    for (int idx = t; idx < N * N; idx += TPB) {
      int row = idx / N, col = idx - row * N;
      float vv = 0.0f;
      if (col > row) vv = wsf[OFS_IOU + b * N * N + idx];
      sm.e.siou[idx] = vv;
    }
    if (t < N) { sm.e.sconf[t] = wsf[OFS_SCONF + b * N + t]; sm.e.mbits[t] = 0u; }
    __syncthreads();
    for (int idx = t; idx < N * N; idx += TPB) {
      int col = idx % N;
      atomicMax(&sm.e.mbits[col], __float_as_uint(sm.e.siou[idx]));
    }
    __syncthreads();
    if (t < N) {
      unsigned int vb = sm.e.mbits[t];
      int rank = 0;
      for (int j2 = 0; j2 < N; j2++) {
        unsigned int jb = sm.e.mbits[j2];
        rank += (jb < vb || (jb == vb && j2 < t)) ? 1 : 0;   // val asc, idx asc
      }
      if (rank < K) sm.e.keep[rank] = t;
    }
    __syncthreads();
    if (t < K) {
      int r = sm.e.keep[t];
      float c = sm.e.sconf[r];
      wsf[OFS_KCONF + b * K + t] = c;
      const float* kl2 = &wsf[OFS_SLOC + (b * N + r) * 4];
      float ael = 0.25f * (kl2[0] * kl2[0] + kl2[1] * kl2[1] +
                           kl2[2] * kl2[2] + kl2[3] * kl2[3]);
      sm.e.coef[t] = ael * c;
    }
    if (t < K * 4) {
      int k = t >> 2, d = t & 3;
      wsf[OFS_KLOC + (b * K + k) * 4 + d] =
          wsf[OFS_SLOC + (b * N + sm.e.keep[k]) * 4 + d];
    }
    for (int q = t; q < K * DM; q += TPB) {
      int k = q >> 5, d = q & 31;
      int orig_i = wsi[IOFS_IDX + b * N + sm.e.keep[k]];
      wsf[OFS_KMASK + (b * K + k) * DM + d] = mask[(b * P + orig_i) * DM + d];
    }
    __syncthreads();

    float acc = 0.0f;
    for (int kc = t; kc < K * N; kc += TPB) {
      int k = kc / N, c = kc - k * N;
      int r = sm.e.keep[k];
      if (c > r) acc += sm.e.siou[r * N + c] * sm.e.sconf[c] * sm.e.coef[k];
    }
    for (int off = 32; off > 0; off >>= 1) acc += __shfl_down(acc, off);
    if ((t & 63) == 0) sm.e.red[t >> 6] = acc;
    __syncthreads();
    if (t == 0) {
      float s = 0.0f;
      for (int w2 = 0; w2 < TPB / 64; w2++) s += sm.e.red[w2];
      atomicAdd(out + 1, s * (1.0f / (float)(B * N * N)));
    }
  }
  gridbar(bar);  // 5

  // ---------------- Phase F: final_conf [B,138,138] (overwrites scratch - dead)
  {
    for (int q = t; q < B * K * 4; q += TPB)  sm.f.kl[q] = wsf[OFS_KLOC + q];
    for (int q = t; q < B * K; q += TPB)      sm.f.kc[q] = wsf[OFS_KCONF + q];
    for (int q = t; q < B * K * DM; q += TPB) sm.f.km[q] = wsf[OFS_KMASK + q];
    __syncthreads();
    for (int px = g; px < B * HPP; px += GT) {
      const int b = (px >= HPP) ? 1 : 0;
      const int pix = px - b * HPP;
      const int h = pix / HP, w2 = pix - h * HP;
      float pv[DM];
      const float4* pp = (const float4*)&proto[(size_t)px * DM];
#pragma unroll
      for (int q = 0; q < DM / 4; q++) {
        float4 f4 = pp[q];
        pv[q * 4 + 0] = f4.x; pv[q * 4 + 1] = f4.y;
        pv[q * 4 + 2] = f4.z; pv[q * 4 + 3] = f4.w;
      }
      const float ysv = (h + 0.5f) / 138.0f;
      const float xsv = (w2 + 0.5f) / 138.0f;
      float sum1 = 0.0f, sum2 = 0.0f;
#pragma unroll
      for (int k = 0; k < K; k++) {
        float dot = 0.0f;
#pragma unroll
        for (int d = 0; d < DM; d++) dot += pv[d] * sm.f.km[(b * K + k) * DM + d];
        float a  = 1.0f / (1.0f + expf(-dot));
        float dx = (xsv - sm.f.kl[(b * K + k) * 4 + 0]) / (sm.f.kl[(b * K + k) * 4 + 2] + 1e-4f);
        float dy = (ysv - sm.f.kl[(b * K + k) * 4 + 1]) / (sm.f.kl[(b * K + k) * 4 + 3] + 1e-4f);
        float ug = expf(-0.5f * (dx * dx + dy * dy));
        float att = a * ug * sm.f.kc[b * K + k];
        sum1 += att;
        sum2 += att * att;
      }
      float fc = 1.0f - sum2 / (sum1 + EPS);
      if (fc != fc) fc = 0.0f;
      wsf[OFS_FC + px] = fc;
    }
  }
  gridbar(bar);  // 6

  // ---------------- Phase G: bilinear upsample + weighted variance (grid-wide)
  {
    float acc = 0.0f;
    for (int pix = g; pix < H * W; pix += GT) {
      const int h = pix / W, w2 = pix - h * W;
      const float scl = 138.0f / 550.0f;
      float sy = (h + 0.5f) * scl - 0.5f;
      float sx = (w2 + 0.5f) * scl - 0.5f;
      float fy0 = floorf(sy), fx0 = floorf(sx);
      float wy = sy - fy0, wx = sx - fx0;
      int y0 = max(0, (int)fy0), y1 = min(HP - 1, (int)fy0 + 1);
      int x0 = max(0, (int)fx0), x1 = min(HP - 1, (int)fx0 + 1);
      float r0, r1;
      {
        const float* fc = &wsf[OFS_FC + 0 * HPP];
        float v00 = fc[y0 * HP + x0], v01 = fc[y0 * HP + x1];
        float v10 = fc[y1 * HP + x0], v11 = fc[y1 * HP + x1];
        float top = v00 + (v01 - v00) * wx;
        float bot = v10 + (v11 - v10) * wx;
        r0 = top + (bot - top) * wy;
      }
      {
        const float* fc = &wsf[OFS_FC + 1 * HPP];
        float v00 = fc[y0 * HP + x0], v01 = fc[y0 * HP + x1];
        float v10 = fc[y1 * HP + x0], v11 = fc[y1 * HP + x1];
        float top = v00 + (v01 - v00) * wx;
        float bot = v10 + (v11 - v10) * wx;
        r1 = top + (bot - top) * wy;
      }
      float total = r0 + r1;
      float inv_t  = 1.0f / total;           // wmean divides by total (no eps)
      float inv_te = 1.0f / (total + EPS);   // wvar divides by total+eps
#pragma unroll
      for (int c = 0; c < 3; c++) {
        float o0 = original[((0 * 3 + c) * H + h) * W + w2];
        float o1 = original[((1 * 3 + c) * H + h) * W + w2];
        float wm = (o0 * r0 + o1 * r1) * inv_t;
        float d0 = o0 - wm, d1 = o1 - wm;
        acc += (d0 * d0 * r0 + d1 * d1 * r1) * inv_te;
      }
    }
    for (int off = 32; off > 0; off >>= 1) acc += __shfl_down(acc, off);
    if ((t & 63) == 0) sm.red[t >> 6] = acc;
    __syncthreads();
    if (t == 0) {
      float s = 0.0f;
      for (int w3 = 0; w3 < TPB / 64; w3++) s += sm.red[w3];
      atomicAdd(out + 0, s * ((float)B / (float)HP));
    }
  }
}

// ---------------------------------------------------------------------------
extern "C" void kernel_launch(void* const* d_in, const int* in_sizes, int n_in,
                              void* d_out, int out_size, void* d_ws,
                              size_t ws_size, hipStream_t stream) {
  (void)in_sizes; (void)n_in; (void)out_size; (void)ws_size;
  const float* original = (const float*)d_in[0];
  const float* loc      = (const float*)d_in[1];
  const float* conf     = (const float*)d_in[2];
  const float* mask     = (const float*)d_in[3];
  const float* proto    = (const float*)d_in[4];
  float* out = (float*)d_out;
  float* wsf = (float*)d_ws;
  int*   wsi = (int*)d_ws;

  // zero the grid-barrier counter and the histogram+count scratch
  hipMemsetAsync((char*)d_ws + (size_t)OFS_BAR * 4, 0, 4, stream);
  hipMemsetAsync((char*)d_ws + (size_t)SC_HIST * 4, 0,
                 (size_t)(B * NBIN + B) * 4, stream);

  k_fused<<<GRID, TPB, 0, stream>>>(original, loc, conf, mask, proto,
                                    wsf, wsi, out);
}

// Round 3
// 217.066 us; speedup vs baseline: 1.5358x; 1.5358x over previous
//
#include <hip/hip_runtime.h>
#include <math.h>

// Problem constants (from reference setup_inputs)
constexpr int B   = 2;
constexpr int P   = 19248;
constexpr int N   = 100;   // TOP_K_CONF
constexpr int K   = 20;    // TOP_K_IOU
constexpr int HP  = 138;   // proto H/W
constexpr int HPP = HP * HP;
constexpr int H   = 550;
constexpr int W   = 550;
constexpr int DM  = 32;    // mask dim
constexpr float EPS = 1e-6f;
constexpr int NBIN = 2048;      // histogram bins over f32 bitpattern >> 19
constexpr int CAND = 2048;      // candidate cap (expected ~150/batch)
constexpr int NPAIR = N * (N - 1) / 2;  // 4950
constexpr int HW = H * W;

constexpr int GRID = 256;       // one block per CU -> all blocks co-resident
constexpr int TPB  = 512;       // 8 waves/block
constexpr int CHUNK = (HW + GRID - 1) / GRID;  // 1182 output px per block

// ---- global workspace (4-byte words). Atomic-only region [0,513); normal
// stores start at word 1024. Total 84 KB (proven ws is far larger).
constexpr int OFS_GMAX = 0;       // uint [B*N]  col-max bits (atomicMax only)
constexpr int OFS_BAR  = 512;     // uint        barrier ticket (atomic only)
constexpr int OFS_IOU  = 1024;    // float [B,N,N] upper-tri (normal stores)

// ---- LDS: persistent block-local results + phase-sequenced union
struct alignas(16) Persist {
  float sconf[B][N];        // top-100 scores
  float sloc[B][N][4];      // top-100 boxes
  int   sidx[B][N];         // top-100 original indices
  float kl[B][K][4];        // kept boxes
  float kc[B][K];           // kept scores
  float km[B][K][DM];       // kept mask coeffs
};
struct SmemA { int h[B][NBIN]; int c[B][NBIN / 16]; int T[B]; };
struct SmemC { float cv[B][CAND]; int ci[B][CAND]; int cnt[B]; };
struct SmemE { unsigned int mb[B][N]; int keepL[B][K]; float coefL[B][K];
               float red[TPB / 64]; };
struct SmemF { float sfc[B][4][HP]; float red[TPB / 64]; };
union  SmemU { SmemA a; SmemC c; SmemE e; SmemF f; };
// union 32.8 KB + persist 10.7 KB = 43.5 KB static LDS

// Grid barrier, ockl-style: RELAXED spin (no per-iteration cache invalidate),
// one release fence before the ticket, one acquire fence after exit.
__device__ __forceinline__ void gridbar(unsigned int* bar) {
  __syncthreads();
  if (threadIdx.x == 0) {
    __threadfence();               // release: wbl2 publishes this block's stores
    unsigned int tk = __hip_atomic_fetch_add(bar, 1u, __ATOMIC_RELAXED,
                                             __HIP_MEMORY_SCOPE_AGENT);
    unsigned int target = (tk / (unsigned)GRID + 1u) * (unsigned)GRID;
    long long guard = 0;
    while (__hip_atomic_load(bar, __ATOMIC_RELAXED,
                             __HIP_MEMORY_SCOPE_AGENT) < target) {
      __builtin_amdgcn_s_sleep(4);
      if (++guard > (50LL << 20)) break;   // ~seconds; never hit legitimately
    }
    __threadfence();               // acquire: single invalidate
  }
  __syncthreads();
}

__device__ __forceinline__ float sig1(float2 c) {
  float m  = fmaxf(c.x, c.y);
  float e0 = expf(c.x - m), e1 = expf(c.y - m);
  return e1 / (e0 + e1);           // bit-identical everywhere it's used
}

__global__ __launch_bounds__(TPB, 2) void k_fused(
    const float* __restrict__ original, const float* __restrict__ loc,
    const float* __restrict__ conf, const float* __restrict__ mask,
    const float* __restrict__ proto, float* wsf, unsigned int* wsu,
    float* out) {
  const int t   = threadIdx.x;
  const int bid = blockIdx.x;
  unsigned int* bar = &wsu[OFS_BAR];
  __shared__ Persist ps;
  __shared__ SmemU sm;

  if (bid == 0 && t < 2)
    __hip_atomic_store(out + t, 0.0f, __ATOMIC_RELAXED,
                       __HIP_MEMORY_SCOPE_AGENT);

  // ============ Phase A (block-redundant): sigmoid -> LDS histogram ============
  {
    int* hh = &sm.a.h[0][0];
    for (int q = t; q < B * NBIN; q += TPB) hh[q] = 0;
  }
  __syncthreads();
  const float2* c2 = (const float2*)conf;
  for (int q = t; q < B * P; q += TPB) {
    float v = sig1(c2[q]);
    int b = (q >= P) ? 1 : 0;
    atomicAdd(&sm.a.h[b][__float_as_uint(v) >> 19], 1);
  }
  __syncthreads();
  // threshold: smallest bin with cumulative-from-top >= N (== serial scan)
  for (int b = 0; b < B; b++) {
    if (t < NBIN / 16) {
      int s = 0;
      for (int u = 0; u < 16; u++) s += sm.a.h[b][t * 16 + u];
      sm.a.c[b][t] = s;
    }
  }
  __syncthreads();
  if (t < B) {
    const int b = t;
    int acc = 0, ch = NBIN / 16 - 1;
    for (; ch >= 0; ch--) { int cs = sm.a.c[b][ch]; if (acc + cs >= N) break; acc += cs; }
    int T = 0;
    if (ch >= 0) {
      int bin = ch * 16 + 15;
      for (; bin >= ch * 16; bin--) { acc += sm.a.h[b][bin]; if (acc >= N) break; }
      T = bin;
    }
    sm.a.T[b] = T;
  }
  __syncthreads();
  const int T0 = sm.a.T[0], T1 = sm.a.T[1];
  __syncthreads();   // all reads of sm.a done before union reuse

  // ============ Phase B (block-redundant): compact candidates to LDS ============
  if (t < B) sm.c.cnt[t] = 0;
  __syncthreads();
  for (int q = t; q < B * P; q += TPB) {
    float v = sig1(c2[q]);           // identical recompute
    int b = (q >= P) ? 1 : 0;
    if ((int)(__float_as_uint(v) >> 19) >= (b ? T1 : T0)) {
      int pos = atomicAdd(&sm.c.cnt[b], 1);
      if (pos < CAND) { sm.c.cv[b][pos] = v; sm.c.ci[b][pos] = q - b * P; }
    }
  }
  __syncthreads();

  // ============ Phase C (block-redundant): rank-based stable top-N ============
  for (int b = 0; b < B; b++) {
    const int M = min(sm.c.cnt[b], CAND);
    for (int c = t; c < M; c += TPB) {
      float mv = sm.c.cv[b][c]; int mi = sm.c.ci[b][c];
      int rank = 0;
      for (int j2 = 0; j2 < M; j2++) {
        float jv = sm.c.cv[b][j2]; int ji = sm.c.ci[b][j2];
        rank += (jv > mv || (jv == mv && ji < mi)) ? 1 : 0;  // val desc, idx asc
      }
      if (rank < N) { ps.sconf[b][rank] = mv; ps.sidx[b][rank] = mi; }
    }
  }
  __syncthreads();
  for (int q = t; q < B * N * 4; q += TPB) {
    int b = q / (N * 4), rr = q - b * N * 4, k = rr >> 2, d = rr & 3;
    ps.sloc[b][k][d] = loc[((size_t)(b * P + ps.sidx[b][k])) * 4 + d];
  }
  __syncthreads();

  // ============ Phase D (grid-partitioned): gaussian IoU, 1 pair/wave ============
  // Reduction tree bit-identical to the proven 256-thread kernel.
  {
    const int wid  = (bid << 3) + (t >> 6);   // 2048 waves
    const int lane = t & 63;
    for (int pr = wid; pr < B * NPAIR; pr += GRID * 8) {
      const int b = (pr >= NPAIR) ? 1 : 0;
      const int r = pr - b * NPAIR;
      int i = (int)((199.0f - sqrtf((float)(39601 - 8 * r))) * 0.5f);
      i = min(max(i, 0), N - 2);
      while (i < N - 2 && ((i + 1) * (2 * N - 2 - i)) / 2 <= r) i++;
      while (i > 0 && (i * (2 * N - 1 - i)) / 2 > r) i--;
      const int j = i + 1 + (r - (i * (2 * N - 1 - i)) / 2);

      const float4 li = *(const float4*)&ps.sloc[b][i][0];
      const float4 lj = *(const float4*)&ps.sloc[b][j][0];

      float smn[4], ssi[4], ssj[4];
#pragma unroll
      for (int w4 = 0; w4 < 4; w4++) {
        smn[w4] = 0.0f; ssi[w4] = 0.0f; ssj[w4] = 0.0f;
#pragma unroll
        for (int q = 0; q < 4; q++) {
          int pix = lane + (w4 << 6) + (q << 8);
          int y = pix >> 5, x = pix & 31;
          float xs = (x + 0.5f) / 32.0f, ys = (y + 0.5f) / 32.0f;
          float dxi = (xs - li.x) / (li.z + 1e-4f);
          float dyi = (ys - li.y) / (li.w + 1e-4f);
          float gi = expf(-0.5f * (dxi * dxi + dyi * dyi));
          float dxj = (xs - lj.x) / (lj.z + 1e-4f);
          float dyj = (ys - lj.y) / (lj.w + 1e-4f);
          float gj = expf(-0.5f * (dxj * dxj + dyj * dyj));
          smn[w4] += fminf(gi, gj);
          ssi[w4] += gi;
          ssj[w4] += gj;
        }
      }
#pragma unroll
      for (int off = 32; off > 0; off >>= 1) {
#pragma unroll
        for (int w4 = 0; w4 < 4; w4++) {
          smn[w4] += __shfl_down(smn[w4], off);
          ssi[w4] += __shfl_down(ssi[w4], off);
          ssj[w4] += __shfl_down(ssj[w4], off);
        }
      }
      if (lane == 0) {
        float inter = smn[0] + smn[1] + smn[2] + smn[3];
        float si    = ssi[0] + ssi[1] + ssi[2] + ssi[3];
        float sj    = ssj[0] + ssj[1] + ssj[2] + ssj[3];
        float iou   = inter / (si + sj - inter);
        wsf[OFS_IOU + (b * N + i) * N + j] = iou;
        atomicMax(&wsu[OFS_GMAX + b * N + j], __float_as_uint(iou));
      }
    }
  }

  gridbar(bar);   // the ONLY grid barrier

  // ============ Phase E (block-redundant): NMS select + gathers ============
  {
    unsigned int* mbf = &sm.e.mb[0][0];
    for (int q = t; q < B * N; q += TPB) mbf[q] = wsu[OFS_GMAX + q];
  }
  __syncthreads();
  if (t < B * N) {
    int b = t / N, col = t - b * N;
    unsigned int vb = sm.e.mb[b][col];
    int rank = 0;
    for (int j2 = 0; j2 < N; j2++) {
      unsigned int jb = sm.e.mb[b][j2];
      rank += (jb < vb || (jb == vb && j2 < col)) ? 1 : 0;   // val asc, idx asc
    }
    if (rank < K) sm.e.keepL[b][rank] = col;
  }
  __syncthreads();
  if (t < B * K) {
    int b = t / K, k = t - b * K;
    int r = sm.e.keepL[b][k];
    float c = ps.sconf[b][r];
    ps.kc[b][k] = c;
    float l0 = ps.sloc[b][r][0], l1 = ps.sloc[b][r][1];
    float l2 = ps.sloc[b][r][2], l3 = ps.sloc[b][r][3];
    sm.e.coefL[b][k] = 0.25f * (l0 * l0 + l1 * l1 + l2 * l2 + l3 * l3) * c;
  }
  if (t < B * K * 4) {
    int b = t / (K * 4), rr = t - b * K * 4, k = rr >> 2, d = rr & 3;
    ps.kl[b][k][d] = ps.sloc[b][sm.e.keepL[b][k]][d];
  }
  for (int q = t; q < B * K * DM; q += TPB) {
    int b = q / (K * DM), rr = q - b * K * DM, k = rr >> 5, d = rr & 31;
    int orig = ps.sidx[b][sm.e.keepL[b][k]];
    ps.km[b][k][d] = mask[((size_t)(b * P + orig)) * DM + d];
  }
  __syncthreads();
  // ae loss: blocks 0,1 only (they have identical keep/coef as everyone)
  if (bid < B) {
    const int b = bid;
    float acc = 0.0f;
    for (int kc2 = t; kc2 < K * N; kc2 += TPB) {
      int k = kc2 / N, c = kc2 - k * N;
      int r = sm.e.keepL[b][k];
      if (c > r)
        acc += wsf[OFS_IOU + (b * N + r) * N + c] * ps.sconf[b][c] *
               sm.e.coefL[b][k];
    }
    for (int off = 32; off > 0; off >>= 1) acc += __shfl_down(acc, off);
    if ((t & 63) == 0) sm.e.red[t >> 6] = acc;
    __syncthreads();
    if (t == 0) {
      float s = 0.0f;
      for (int w2 = 0; w2 < TPB / 64; w2++) s += sm.e.red[w2];
      atomicAdd(out + 1, s * (1.0f / (float)(B * N * N)));
    }
  }
  __syncthreads();   // sm.e dead before union reuse

  // ============ Phase F (tiled): final_conf rows this block needs, in LDS ====
  const int p0 = bid * CHUNK;
  const int p1 = min(p0 + CHUNK, HW);
  const int h0 = p0 / W, h1 = (p1 - 1) / W;
  const float scl = 138.0f / 550.0f;
  const int ylo = max(0, (int)floorf((h0 + 0.5f) * scl - 0.5f));
  const int yhi = min(HP - 1, (int)floorf((h1 + 0.5f) * scl - 0.5f) + 1);
  const int nrows = yhi - ylo + 1;   // <= 3 (alloc 4)
  for (int idx = t; idx < B * nrows * HP; idx += TPB) {
    int b  = idx / (nrows * HP);
    int rr = idx - b * nrows * HP;
    int ry = rr / HP, xx = rr - ry * HP;
    int yy = ylo + ry;
    float pv[DM];
    const float4* pp = (const float4*)&proto[(size_t)(b * HPP + yy * HP + xx) * DM];
#pragma unroll
    for (int q = 0; q < DM / 4; q++) {
      float4 f4 = pp[q];
      pv[q * 4 + 0] = f4.x; pv[q * 4 + 1] = f4.y;
      pv[q * 4 + 2] = f4.z; pv[q * 4 + 3] = f4.w;
    }
    const float ysv = (yy + 0.5f) / 138.0f;
    const float xsv = (xx + 0.5f) / 138.0f;
    float sum1 = 0.0f, sum2 = 0.0f;
#pragma unroll
    for (int k = 0; k < K; k++) {
      float dot = 0.0f;
#pragma unroll
      for (int d = 0; d < DM; d++) dot += pv[d] * ps.km[b][k][d];
      float a  = 1.0f / (1.0f + expf(-dot));
      float dx = (xsv - ps.kl[b][k][0]) / (ps.kl[b][k][2] + 1e-4f);
      float dy = (ysv - ps.kl[b][k][1]) / (ps.kl[b][k][3] + 1e-4f);
      float ug = expf(-0.5f * (dx * dx + dy * dy));
      float att = a * ug * ps.kc[b][k];
      sum1 += att;
      sum2 += att * att;
    }
    float fc = 1.0f - sum2 / (sum1 + EPS);
    if (fc != fc) fc = 0.0f;
    sm.f.sfc[b][ry][xx] = fc;
  }
  __syncthreads();

  // ============ Phase G: bilinear upsample + weighted variance ============
  {
    float acc = 0.0f;
    for (int pix = p0 + t; pix < p1; pix += TPB) {
      const int h = pix / W, w2 = pix - h * W;
      float sy = (h + 0.5f) * scl - 0.5f;
      float sx = (w2 + 0.5f) * scl - 0.5f;
      float fy0 = floorf(sy), fx0 = floorf(sx);
      float wy = sy - fy0, wx = sx - fx0;
      int y0 = max(0, (int)fy0), y1 = min(HP - 1, (int)fy0 + 1);
      int x0 = max(0, (int)fx0), x1 = min(HP - 1, (int)fx0 + 1);
      int ry0 = y0 - ylo, ry1 = y1 - ylo;
      float r0, r1;
      {
        float v00 = sm.f.sfc[0][ry0][x0], v01 = sm.f.sfc[0][ry0][x1];
        float v10 = sm.f.sfc[0][ry1][x0], v11 = sm.f.sfc[0][ry1][x1];
        float top = v00 + (v01 - v00) * wx;
        float bot = v10 + (v11 - v10) * wx;
        r0 = top + (bot - top) * wy;
      }
      {
        float v00 = sm.f.sfc[1][ry0][x0], v01 = sm.f.sfc[1][ry0][x1];
        float v10 = sm.f.sfc[1][ry1][x0], v11 = sm.f.sfc[1][ry1][x1];
        float top = v00 + (v01 - v00) * wx;
        float bot = v10 + (v11 - v10) * wx;
        r1 = top + (bot - top) * wy;
      }
      float total = r0 + r1;
      float inv_t  = 1.0f / total;           // wmean divides by total (no eps)
      float inv_te = 1.0f / (total + EPS);   // wvar divides by total+eps
#pragma unroll
      for (int c = 0; c < 3; c++) {
        float o0 = original[((0 * 3 + c) * H + h) * W + w2];
        float o1 = original[((1 * 3 + c) * H + h) * W + w2];
        float wm = (o0 * r0 + o1 * r1) * inv_t;
        float d0 = o0 - wm, d1 = o1 - wm;
        acc += (d0 * d0 * r0 + d1 * d1 * r1) * inv_te;
      }
    }
    for (int off = 32; off > 0; off >>= 1) acc += __shfl_down(acc, off);
    if ((t & 63) == 0) sm.f.red[t >> 6] = acc;
    __syncthreads();
    if (t == 0) {
      float s = 0.0f;
      for (int w3 = 0; w3 < TPB / 64; w3++) s += sm.f.red[w3];
      atomicAdd(out + 0, s * ((float)B / (float)HP));
    }
  }
}

// ---------------------------------------------------------------------------
extern "C" void kernel_launch(void* const* d_in, const int* in_sizes, int n_in,
                              void* d_out, int out_size, void* d_ws,
                              size_t ws_size, hipStream_t stream) {
  (void)in_sizes; (void)n_in; (void)out_size; (void)ws_size;
  const float* original = (const float*)d_in[0];
  const float* loc      = (const float*)d_in[1];
  const float* conf     = (const float*)d_in[2];
  const float* mask     = (const float*)d_in[3];
  const float* proto    = (const float*)d_in[4];
  float* out = (float*)d_out;
  float* wsf = (float*)d_ws;
  unsigned int* wsu = (unsigned int*)d_ws;

  // zero gmax + barrier ticket (atomic-only region, words [0, 513))
  hipMemsetAsync(d_ws, 0, (size_t)(OFS_BAR + 1) * 4, stream);

  k_fused<<<GRID, TPB, 0, stream>>>(original, loc, conf, mask, proto,
                                    wsf, wsu, out);
}